// Round 2
// baseline (2272.919 us; speedup 1.0000x reference)
//
#include <hip/hip_runtime.h>
#include <hip/hip_bf16.h>

// TinyGRU: x[2048,512] int -> emb[95,48] -> GRU(H=48) -> logits[.,.,95] (+ h_last)
//  A) xg_table[95][144] = emb @ w_ih^T + b_ih  (55 KB in d_ws)
//  B) recurrence: 1 block = 1 wave per batch row; lane j<48 owns gate rows
//     {j,j+48,j+96}; w_hh stationary in 144 VGPRs; h broadcast via uniform LDS
//     reads. NO __syncthreads (single wave; same-wave LDS ops are in-order and
//     hsh[j] write aliases all reads -> compiler preserves ordering; pinned with
//     wave_barrier). Global stash store drains in background (no vmcnt(0)).
//     h_t stashed in first 48 floats of each 95-wide logits row of d_out.
//  C) logits: 64 positions/block, 256 thr; stash->LDS (stride 52 pad), h row in
//     48 VGPRs, wave-uniform v -> scalar w_out loads, 64x95 LDS tile flushed as
//     contiguous coalesced float4 stores (in-place over own tile only).

#define BATCH 2048
#define SEQ   512
#define HDIM  48
#define VOCAB 95
#define G3    144   // 3*HDIM
#define HPAD  52    // LDS row stride for h tile (13 float4s, coprime w/ 8 bank-groups)

__device__ __forceinline__ float sigmoidf_(float x) {
    return 1.0f / (1.0f + __expf(-x));
}
__device__ __forceinline__ float fast_tanh(float x) {
    float ax = fabsf(x);
    float e  = __expf(-2.0f * ax);
    float r  = (1.0f - e) / (1.0f + e);
    return copysignf(r, x);
}

// ---------------- Kernel A: xg_table precompute ----------------
__global__ void xg_precompute(const float* __restrict__ emb,
                              const float* __restrict__ w_ih,
                              const float* __restrict__ b_ih,
                              float* __restrict__ xg) {
    int v = blockIdx.x;    // 0..94
    int g = threadIdx.x;   // 0..143
    const float* e = emb + v * HDIM;      // wave-uniform -> scalar loads
    const float* w = w_ih + g * HDIM;     // per-lane
    float a0 = 0.f, a1 = 0.f, a2 = 0.f, a3 = 0.f;
    #pragma unroll
    for (int k = 0; k < HDIM; k += 4) {
        a0 = fmaf(w[k + 0], e[k + 0], a0);
        a1 = fmaf(w[k + 1], e[k + 1], a1);
        a2 = fmaf(w[k + 2], e[k + 2], a2);
        a3 = fmaf(w[k + 3], e[k + 3], a3);
    }
    xg[v * G3 + g] = b_ih[g] + ((a0 + a1) + (a2 + a3));
}

// ---------------- Kernel B: GRU recurrence (1 wave / row) ----------------
__global__ __launch_bounds__(64, 2)
void gru_rec(const int* __restrict__ x,
             const float* __restrict__ xg_table,
             const float* __restrict__ w_hh,
             const float* __restrict__ b_hh,
             float* __restrict__ out,       // h_t stash in head of each 95-wide row
             float* __restrict__ hidden) {  // [BATCH*HDIM]
    const int row = blockIdx.x;
    const int j   = threadIdx.x;   // active for j<48
    __shared__ float hsh[HDIM];

    float4 wr[12], wz[12], wn[12];
    float br = 0.f, bz = 0.f, bn = 0.f;
    float hj = 0.f;
    if (j < HDIM) {
        const float4* whr = (const float4*)(w_hh + (j         ) * HDIM);
        const float4* whz = (const float4*)(w_hh + (j +   HDIM) * HDIM);
        const float4* whn = (const float4*)(w_hh + (j + 2*HDIM) * HDIM);
        #pragma unroll
        for (int k = 0; k < 12; ++k) { wr[k] = whr[k]; wz[k] = whz[k]; wn[k] = whn[k]; }
        br = b_hh[j]; bz = b_hh[j + HDIM]; bn = b_hh[j + 2*HDIM];
        hsh[j] = 0.f;
    }
    __builtin_amdgcn_wave_barrier();

    const int* xrow = x + row * SEQ;
    float* orow = out + (long)row * SEQ * VOCAB + j;

    // preload xg for t=0
    int tok0 = xrow[0];
    float xr = 0.f, xz = 0.f, xn = 0.f;
    if (j < HDIM) {
        const float* xg0 = xg_table + tok0 * G3;
        xr = xg0[j]; xz = xg0[j + HDIM]; xn = xg0[j + 2*HDIM];
    }

    for (int t = 0; t < SEQ; ++t) {
        // prefetch next timestep's xg row (hides L2 latency behind compute)
        int tok_next = (t + 1 < SEQ) ? xrow[t + 1] : 0;
        const float* xgn = xg_table + tok_next * G3;
        float xr_n = 0.f, xz_n = 0.f, xn_n = 0.f;
        if (j < HDIM) { xr_n = xgn[j]; xz_n = xgn[j + HDIM]; xn_n = xgn[j + 2*HDIM]; }

        float hnew = 0.f;
        if (j < HDIM) {
            float accr = br, accz = bz, accn = bn;
            const float4* h4 = (const float4*)hsh;   // uniform addr -> broadcast
            #pragma unroll
            for (int k = 0; k < 12; ++k) {
                float4 hh = h4[k];
                accr = fmaf(wr[k].x, hh.x, accr); accr = fmaf(wr[k].y, hh.y, accr);
                accr = fmaf(wr[k].z, hh.z, accr); accr = fmaf(wr[k].w, hh.w, accr);
                accz = fmaf(wz[k].x, hh.x, accz); accz = fmaf(wz[k].y, hh.y, accz);
                accz = fmaf(wz[k].z, hh.z, accz); accz = fmaf(wz[k].w, hh.w, accz);
                accn = fmaf(wn[k].x, hh.x, accn); accn = fmaf(wn[k].y, hh.y, accn);
                accn = fmaf(wn[k].z, hh.z, accn); accn = fmaf(wn[k].w, hh.w, accn);
            }
            float r = sigmoidf_(xr + accr);
            float z = sigmoidf_(xz + accz);
            float n = fast_tanh(xn + r * accn);
            hnew = (1.0f - z) * n + z * hj;
            hj = hnew;
            orow[(long)t * VOCAB] = hnew;   // background store, no drain needed
        }
        __builtin_amdgcn_wave_barrier();    // pin ordering: reads above, write below
        if (j < HDIM) hsh[j] = hnew;
        __builtin_amdgcn_wave_barrier();
        xr = xr_n; xz = xz_n; xn = xn_n;
    }
    if (j < HDIM) hidden[row * HDIM + j] = hj;
}

// ---------------- Kernel C: logits projection (in-place over stash) ----------------
#define PTILE 64
__global__ __launch_bounds__(256, 4)
void logits_k(const float* __restrict__ w_out,
              const float* __restrict__ b_out,
              float* __restrict__ out) {
    __shared__ float hsh[PTILE * HPAD];      // 13.3 KB
    __shared__ float ltile[PTILE * VOCAB];   // 24.3 KB (mirrors global layout)
    const long pos0 = (long)blockIdx.x * PTILE;
    const int tid = threadIdx.x;

    // stage stash rows (first 48 of each 95-wide row) into LDS
    for (int i = tid; i < PTILE * HDIM; i += 256) {
        int p = i / HDIM;
        int k = i - p * HDIM;
        hsh[p * HPAD + k] = out[(pos0 + p) * VOCAB + k];
    }
    __syncthreads();

    // wave w handles vocab group, lane = position
    const int lane = tid & 63;
    const int w    = tid >> 6;          // wave-uniform
    const int vstart = w * 24;
    const int vend   = (vstart + 24 < VOCAB) ? vstart + 24 : VOCAB;

    float h[HDIM];
    #pragma unroll
    for (int k = 0; k < 12; ++k)
        ((float4*)h)[k] = ((const float4*)(hsh + lane * HPAD))[k];

    for (int v = vstart; v < vend; ++v) {
        const float* wv = w_out + v * HDIM;   // wave-uniform -> scalar loads
        float a0 = 0.f, a1 = 0.f, a2 = 0.f, a3 = 0.f;
        #pragma unroll
        for (int k = 0; k < HDIM; k += 4) {
            a0 = fmaf(wv[k + 0], h[k + 0], a0);
            a1 = fmaf(wv[k + 1], h[k + 1], a1);
            a2 = fmaf(wv[k + 2], h[k + 2], a2);
            a3 = fmaf(wv[k + 3], h[k + 3], a3);
        }
        ltile[lane * VOCAB + v] = b_out[v] + ((a0 + a1) + (a2 + a3));
    }
    __syncthreads();

    // coalesced contiguous flush: 64*95 = 6080 floats = 1520 float4
    float4* dst = (float4*)(out + pos0 * VOCAB);
    const float4* src = (const float4*)ltile;
    for (int i = tid; i < (PTILE * VOCAB) / 4; i += 256)
        dst[i] = src[i];
}

extern "C" void kernel_launch(void* const* d_in, const int* in_sizes, int n_in,
                              void* d_out, int out_size, void* d_ws, size_t ws_size,
                              hipStream_t stream) {
    const int*   x     = (const int*)d_in[0];
    const float* emb   = (const float*)d_in[1];
    const float* w_ih  = (const float*)d_in[2];
    const float* w_hh  = (const float*)d_in[3];
    const float* b_ih  = (const float*)d_in[4];
    const float* b_hh  = (const float*)d_in[5];
    const float* w_out = (const float*)d_in[6];
    const float* b_out = (const float*)d_in[7];

    float* out    = (float*)d_out;
    float* hidden = out + (long)BATCH * SEQ * VOCAB;
    float* xg     = (float*)d_ws;   // 95*144*4 = 54,720 B

    xg_precompute<<<VOCAB, G3, 0, stream>>>(emb, w_ih, b_ih, xg);
    gru_rec<<<BATCH, 64, 0, stream>>>(x, xg, w_hh, b_hh, out, hidden);
    logits_k<<<(BATCH * SEQ) / PTILE, 256, 0, stream>>>(w_out, b_out, out);
}